// Round 9
// baseline (79.407 us; speedup 1.0000x reference)
//
#include <hip/hip_runtime.h>
#include <hip/hip_bf16.h>
#include <hip/hip_cooperative_groups.h>

// RGCN fused: out = relu( [x | agg_r0..agg_r15] @ [w_self | w_rel]^T )
// B=4096, S=10, R=16, F=128, K_total=2176.
// v9: cooperative single kernel. Blocks 0..33 pre-pack W into bf16 fragment
// layout (w2, in d_ws) -- the coalescing-critical layout R8 proved necessary
// -- overlapped with masks/gathers/phase A; grid.sync() before phase B makes
// w2 visible grid-wide. Phases A0/A/B/C/D are v6 VERBATIM (20.97 us kernel).

namespace cg = cooperative_groups;

#define BT   16
#define LDA  2184            // bf16 elems per A_t row (2176 + 8 pad)
#define NTHR 1024

typedef __attribute__((ext_vector_type(8))) short short8;  // 8 bf16
typedef __attribute__((ext_vector_type(4))) float f32x4;   // MFMA acc

__device__ __forceinline__ unsigned int pk2_rne(float lo, float hi) {
  unsigned int r;
  asm("v_cvt_pk_bf16_f32 %0, %1, %2" : "=v"(r) : "v"(lo), "v"(hi));
  return r;
}

// Workgroup barrier draining LDS ops only — global loads stay in flight.
__device__ __forceinline__ void barrier_lgkm() {
  __builtin_amdgcn_sched_barrier(0);
  asm volatile("s_waitcnt lgkmcnt(0)" ::: "memory");
  __builtin_amdgcn_s_barrier();
  __builtin_amdgcn_sched_barrier(0);
}

__global__ __launch_bounds__(NTHR)
void rgcn_coop(const float* __restrict__ emb,
               const float* __restrict__ w_self,
               const float* __restrict__ w_rel,
               const int*   __restrict__ nodes,
               const int*   __restrict__ neighbors,
               const int*   __restrict__ rel_mask,
               uint4*       w2,
               float*       __restrict__ out)
{
  __shared__ alignas(16) char smem[80128];
  unsigned short* A_t = (unsigned short*)smem;                  // [16][2184] bf16
  float* P = (float*)smem;                                      // P0 [16][132]; P1 at +2112 words
  float (*mscale)[10][16] = (float (*)[10][16])(smem + 69888);  // [16][10][16]

  const int t   = threadIdx.x;
  const int l   = t & 63;
  const int w   = t >> 6;          // wave 0..15
  const int bid = blockIdx.x;
  const int b0  = bid * BT;

  // phase-B identity: wave = (o-group of 2 tiles) x (k-quarter of 17 ks)
  const int og  = w & 3,  kq = w >> 2;
  const int ot0 = og * 2;
  const int ksq = kq * 17;
  const int ln  = l & 15, lj = l >> 4;
  const int o0c = ot0 * 16 + ln;
  const int o1c = o0c + 16;

  // ---------- W pre-pack: blocks 0..33, wave w converts unit u=bid*16+w ----------
  // (544 units total; issued first so the stores retire long before grid.sync)
  if (bid < 34) {
    const int u  = bid * 16 + w;          // 0..543
    const int ks = u >> 3, ot = u & 7;
    const int o  = ot * 16 + ln;
    const int k0 = ks * 32 + lj * 8;
    const float* src;
    if (k0 < 128) src = w_self + o * 128 + k0;
    else {
      const int r = (k0 - 128) >> 7, kc = (k0 - 128) & 127;
      src = w_rel + ((size_t)(r * 128 + o)) * 128 + kc;
    }
    const float4 a = *(const float4*)src;
    const float4 b = *(const float4*)(src + 4);
    uint4 v;
    v.x = pk2_rne(a.x, a.y); v.y = pk2_rne(a.z, a.w);
    v.z = pk2_rne(b.x, b.y); v.w = pk2_rne(b.z, b.w);
    w2[u * 64 + l] = v;
    __threadfence();                      // agent-scope release of w2 stores
  }

  // ---------- index loads (first: gathers depend on them) ----------
  const int bi   = w;              // node slot 0..15 (one per wave)
  const int b    = b0 + bi;
  const int node = nodes[b];
  int nb[10];
  {
    const int2* np = (const int2*)(neighbors + (size_t)b * 10);  // 8B-aligned (40B stride)
    const int2 p0 = np[0], p1 = np[1], p2 = np[2], p3 = np[3], p4 = np[4];
    nb[0]=p0.x; nb[1]=p0.y; nb[2]=p1.x; nb[3]=p1.y; nb[4]=p2.x;
    nb[5]=p2.y; nb[6]=p3.x; nb[7]=p3.y; nb[8]=p4.x; nb[9]=p4.y;
  }

  // ---------- mask loads (waves 0-3 cover 16 nodes x 16 relations) ----------
  int mb[10];
  if (t < 256) {
    const int* mp = rel_mask + (size_t)(b0 + (t >> 4)) * 160 + (t & 15);
    #pragma unroll
    for (int s = 0; s < 10; ++s) mb[s] = mp[s * 16];
  }

  // ---------- gathers (issued early; consumed in phase A) ----------
  const int f0 = l * 2;            // 2 features per lane
  float2 ne[10];
  #pragma unroll
  for (int s = 0; s < 10; ++s)
    ne[s] = *(const float2*)(emb + (size_t)nb[s] * 128 + f0);
  const float2 x2 = *(const float2*)(emb + (size_t)node * 128 + f0);

  // ---------- mscale[b][s][r] = m/(count+eps) ----------
  if (t < 256) {
    int c = 0;
    #pragma unroll
    for (int s = 0; s < 10; ++s) c += mb[s];
    const float inv = 1.0f / ((float)c + 1e-10f);
    #pragma unroll
    for (int s = 0; s < 10; ++s) mscale[t >> 4][s][t & 15] = mb[s] ? inv : 0.0f;
  }
  barrier_lgkm();

  // ---------- Phase A: wave w builds A_t row w (self + 16 masked means) ----------
  {
    char* arow = (char*)A_t + bi * (LDA * 2);
    *(unsigned int*)(arow + f0 * 2) = pk2_rne(x2.x, x2.y);     // self, k in [0,128)
    float acc[16][2];
    #pragma unroll
    for (int r = 0; r < 16; ++r) { acc[r][0] = 0.f; acc[r][1] = 0.f; }
    #pragma unroll
    for (int s = 0; s < 10; ++s) {
      const float4 m0 = *(const float4*)(&mscale[bi][s][0]);   // uniform -> LDS broadcast
      const float4 m1 = *(const float4*)(&mscale[bi][s][4]);
      const float4 m2 = *(const float4*)(&mscale[bi][s][8]);
      const float4 m3 = *(const float4*)(&mscale[bi][s][12]);
      const float m[16] = {m0.x,m0.y,m0.z,m0.w, m1.x,m1.y,m1.z,m1.w,
                           m2.x,m2.y,m2.z,m2.w, m3.x,m3.y,m3.z,m3.w};
      const float2 v = ne[s];
      #pragma unroll
      for (int r = 0; r < 16; ++r) {
        acc[r][0] += m[r] * v.x;
        acc[r][1] += m[r] * v.y;
      }
    }
    #pragma unroll
    for (int r = 0; r < 16; ++r)                               // rel r: k in [128+128r, ...)
      *(unsigned int*)(arow + 256 + r * 256 + f0 * 2) = pk2_rne(acc[r][0], acc[r][1]);
  }
  barrier_lgkm();                  // A_t ready (LDS)

  // ---------- grid-wide sync: w2 fully written & visible (agent acq/rel) ----------
  cg::this_grid().sync();

  // ---------- Phase B: 17 k-steps x 2 o-tiles, 1-deep W2 reg pipeline ----------
  f32x4 accA = {0.f,0.f,0.f,0.f}, accB = {0.f,0.f,0.f,0.f};
  {
    const uint4* wq = w2 + (size_t)((ksq * 8 + ot0) * 64) + l;
    uint4 c0 = wq[0];                // (ksq, ot0)
    uint4 c1 = wq[64];               // (ksq, ot0+1)
    wq += 512;                       // next k-step
    const char* ar = (const char*)A_t + ln * (LDA * 2) + lj * 16;
    #pragma unroll
    for (int i = 0; i < 17; ++i) {
      const short8 a = *(const short8*)(ar + (ksq + i) * 64);  // one read, two MFMAs
      const uint4 n0 = wq[0];                                  // prefetch ks+1 (OOB-safe:
      const uint4 n1 = wq[64];                                 //  tail reads stay in d_ws)
      wq += 512;
      union { uint4 u; short8 s; } u0, u1;
      u0.u = c0; u1.u = c1;
      accA = __builtin_amdgcn_mfma_f32_16x16x32_bf16(a, u0.s, accA, 0, 0, 0);
      accB = __builtin_amdgcn_mfma_f32_16x16x32_bf16(a, u1.s, accB, 0, 0, 0);
      c0 = n0; c1 = n1;
    }
  }
  barrier_lgkm();                  // A_t dead; P0/P1 alias it

  // ---------- Phase C: kq even writes, kq odd accumulates ----------
  {
    float* Pg = P + (kq >> 1) * 2112;          // kq 0,1 -> P0 ; kq 2,3 -> P1
    if ((kq & 1) == 0) {
      #pragma unroll
      for (int j = 0; j < 4; ++j) {
        Pg[(lj*4+j)*132 + o0c] = accA[j];
        Pg[(lj*4+j)*132 + o1c] = accB[j];
      }
    }
    barrier_lgkm();
    if ((kq & 1) == 1) {
      #pragma unroll
      for (int j = 0; j < 4; ++j) {
        Pg[(lj*4+j)*132 + o0c] += accA[j];
        Pg[(lj*4+j)*132 + o1c] += accB[j];
      }
    }
    barrier_lgkm();
  }

  // ---------- Phase D: out = relu(P0 + P1) ----------
  {
    const int row = w;                         // t >> 6
    const int cc  = l * 2;
    const float2 pa = *(const float2*)(P + row * 132 + cc);
    const float2 pb = *(const float2*)(P + 2112 + row * 132 + cc);
    float2 o2;
    o2.x = fmaxf(pa.x + pb.x, 0.f);
    o2.y = fmaxf(pa.y + pb.y, 0.f);
    *(float2*)(out + (size_t)(b0 + row) * 128 + cc) = o2;
  }
}

extern "C" void kernel_launch(void* const* d_in, const int* in_sizes, int n_in,
                              void* d_out, int out_size, void* d_ws, size_t ws_size,
                              hipStream_t stream) {
  const float* emb       = (const float*)d_in[0];
  const float* w_self    = (const float*)d_in[1];
  const float* w_rel     = (const float*)d_in[2];
  const int*   nodes     = (const int*)d_in[3];
  const int*   neighbors = (const int*)d_in[4];
  const int*   rel_mask  = (const int*)d_in[5];
  float* out = (float*)d_out;
  uint4* w2  = (uint4*)d_ws;
  (void)in_sizes; (void)n_in; (void)out_size; (void)ws_size;

  void* args[] = { (void*)&emb, (void*)&w_self, (void*)&w_rel, (void*)&nodes,
                   (void*)&neighbors, (void*)&rel_mask, (void*)&w2, (void*)&out };
  hipLaunchCooperativeKernel((const void*)rgcn_coop, dim3(4096 / BT), dim3(NTHR),
                             args, 0, stream);
}

// Round 10
// 21.641 us; speedup vs baseline: 3.6693x; 3.6693x over previous
//
#include <hip/hip_runtime.h>
#include <hip/hip_bf16.h>

// RGCN fused: out = relu( [x | agg_r0..agg_r15] @ [w_self | w_rel]^T )
// B=4096, S=10, R=16, F=128, K_total=2176.
// v10: v6 (20.97us known-good) + 64KB W2 pre-stage into spare LDS via
// global_load_lds, issued at kernel top (overlaps masks/gathers/phase A).
// Each wave's first 2 of 17 k-steps come from LDS; reg prefetch starts at
// i=2. A->B barrier drains vmcnt once (prestage long done by then).

#define BT   16
#define LDA  2184            // bf16 elems per A_t row (2176 + 8 pad)
#define NTHR 1024
#define WLDS_OFF 80128       // W2LDS region offset in smem

typedef __attribute__((ext_vector_type(8))) short short8;  // 8 bf16
typedef __attribute__((ext_vector_type(4))) float f32x4;   // MFMA acc

__device__ __forceinline__ unsigned int pk2_rne(float lo, float hi) {
  unsigned int r;
  asm("v_cvt_pk_bf16_f32 %0, %1, %2" : "=v"(r) : "v"(lo), "v"(hi));
  return r;
}

// Workgroup barrier draining LDS ops only — global loads stay in flight.
__device__ __forceinline__ void barrier_lgkm() {
  __builtin_amdgcn_sched_barrier(0);
  asm volatile("s_waitcnt lgkmcnt(0)" ::: "memory");
  __builtin_amdgcn_s_barrier();
  __builtin_amdgcn_sched_barrier(0);
}
// Full-drain barrier (used once, at the A->B transition).
__device__ __forceinline__ void barrier_full() {
  __builtin_amdgcn_sched_barrier(0);
  asm volatile("s_waitcnt vmcnt(0) lgkmcnt(0)" ::: "memory");
  __builtin_amdgcn_s_barrier();
  __builtin_amdgcn_sched_barrier(0);
}

// ---- prep: W (fp32) -> bf16 fragments, layout [ks][ot][lane], 16B/lane ----
__global__ __launch_bounds__(256)
void wprep(const float* __restrict__ w_self, const float* __restrict__ w_rel,
           uint4* __restrict__ w2)
{
  const int u  = blockIdx.x * 4 + (threadIdx.x >> 6);   // 0..543
  const int l  = threadIdx.x & 63;
  const int ln = l & 15, lj = l >> 4;
  const int ks = u >> 3, ot = u & 7;
  const int o  = ot * 16 + ln;
  const int k0 = ks * 32 + lj * 8;
  const float* src;
  if (k0 < 128) src = w_self + o * 128 + k0;
  else {
    const int r = (k0 - 128) >> 7, kc = (k0 - 128) & 127;
    src = w_rel + ((size_t)(r * 128 + o)) * 128 + kc;
  }
  const float4 a = *(const float4*)src;
  const float4 b = *(const float4*)(src + 4);
  uint4 v;
  v.x = pk2_rne(a.x, a.y); v.y = pk2_rne(a.z, a.w);
  v.z = pk2_rne(b.x, b.y); v.w = pk2_rne(b.z, b.w);
  w2[u * 64 + l] = v;
}

__global__ __launch_bounds__(NTHR)
void rgcn_fused(const float* __restrict__ emb,
                const int*   __restrict__ nodes,
                const int*   __restrict__ neighbors,
                const int*   __restrict__ rel_mask,
                const uint4* __restrict__ w2,
                float*       __restrict__ out)
{
  __shared__ alignas(16) char smem[145664];
  // [0, 69888)        A_t [16][2184] bf16  (phase C/D: P0/P1 alias this)
  // [69888, 80128)    mscale [16][10][16] f32
  // [80128, 145664)   W2LDS: 64 chunks of 1KB = [kq][i<2][ot][lane] 16B
  unsigned short* A_t = (unsigned short*)smem;
  float* P = (float*)smem;                                      // P0; P1 at +2112 words
  float (*mscale)[10][16] = (float (*)[10][16])(smem + 69888);

  const int t  = threadIdx.x;
  const int l  = t & 63;
  const int w  = t >> 6;           // wave 0..15
  const int b0 = blockIdx.x * BT;

  // phase-B identity: wave = (o-group of 2 tiles) x (k-quarter of 17 ks)
  const int og  = w & 3,  kq = w >> 2;
  const int ot0 = og * 2;
  const int ksq = kq * 17;
  const int ln  = l & 15, lj = l >> 4;
  const int o0c = ot0 * 16 + ln;   // output cols this lane covers
  const int o1c = o0c + 16;

  // ---------- W2 pre-stage: 64KB = first 2 k-steps of each k-quarter ----------
  // chunk c = (kq*2+i)*8+ot  ->  LDS [c][lane], src = w2[(kq*17+i)*8+ot][lane].
  // Issued first: the L2 stream runs under masks/gathers/phase A.
  {
    #pragma unroll
    for (int j = 0; j < 4; ++j) {
      const int c   = j * 16 + w;            // wave-uniform chunk id
      const int ot  = c & 7, ki = c >> 3;
      const int ks  = (ki >> 1) * 17 + (ki & 1);
      const uint4* src = w2 + (size_t)((ks * 8 + ot) * 64) + l;
      char* dst = smem + WLDS_OFF + c * 1024 + l * 16;
      __builtin_amdgcn_global_load_lds((const unsigned int*)src,
                                       (unsigned int*)dst, 16, 0, 0);
    }
  }

  // ---------- index loads (gathers depend on them) ----------
  const int bi   = w;              // node slot 0..15 (one per wave)
  const int b    = b0 + bi;
  const int node = nodes[b];
  int nb[10];
  {
    const int2* np = (const int2*)(neighbors + (size_t)b * 10);  // 8B-aligned (40B stride)
    const int2 p0 = np[0], p1 = np[1], p2 = np[2], p3 = np[3], p4 = np[4];
    nb[0]=p0.x; nb[1]=p0.y; nb[2]=p1.x; nb[3]=p1.y; nb[4]=p2.x;
    nb[5]=p2.y; nb[6]=p3.x; nb[7]=p3.y; nb[8]=p4.x; nb[9]=p4.y;
  }

  // ---------- mask loads (waves 0-3 cover 16 nodes x 16 relations) ----------
  int mb[10];
  if (t < 256) {
    const int* mp = rel_mask + (size_t)(b0 + (t >> 4)) * 160 + (t & 15);
    #pragma unroll
    for (int s = 0; s < 10; ++s) mb[s] = mp[s * 16];
  }

  // ---------- W2 reg prefetch for iteration i=2 of this wave ----------
  const uint4* wq = w2 + (size_t)(((ksq + 2) * 8 + ot0) * 64) + l;
  uint4 c0 = wq[0];                // (ksq+2, ot0)
  uint4 c1 = wq[64];               // (ksq+2, ot0+1)
  wq += 512;                       // -> i=3

  // ---------- gathers (issued early; consumed in phase A) ----------
  const int f0 = l * 2;            // 2 features per lane
  float2 ne[10];
  #pragma unroll
  for (int s = 0; s < 10; ++s)
    ne[s] = *(const float2*)(emb + (size_t)nb[s] * 128 + f0);
  const float2 x2 = *(const float2*)(emb + (size_t)node * 128 + f0);

  // ---------- mscale[b][s][r] = m/(count+eps) ----------
  if (t < 256) {
    int c = 0;
    #pragma unroll
    for (int s = 0; s < 10; ++s) c += mb[s];
    const float inv = 1.0f / ((float)c + 1e-10f);
    #pragma unroll
    for (int s = 0; s < 10; ++s) mscale[t >> 4][s][t & 15] = mb[s] ? inv : 0.0f;
  }
  barrier_lgkm();

  // ---------- Phase A: wave w builds A_t row w (self + 16 masked means) ----------
  {
    char* arow = (char*)A_t + bi * (LDA * 2);
    *(unsigned int*)(arow + f0 * 2) = pk2_rne(x2.x, x2.y);     // self, k in [0,128)
    float acc[16][2];
    #pragma unroll
    for (int r = 0; r < 16; ++r) { acc[r][0] = 0.f; acc[r][1] = 0.f; }
    #pragma unroll
    for (int s = 0; s < 10; ++s) {
      const float4 m0 = *(const float4*)(&mscale[bi][s][0]);   // uniform -> LDS broadcast
      const float4 m1 = *(const float4*)(&mscale[bi][s][4]);
      const float4 m2 = *(const float4*)(&mscale[bi][s][8]);
      const float4 m3 = *(const float4*)(&mscale[bi][s][12]);
      const float m[16] = {m0.x,m0.y,m0.z,m0.w, m1.x,m1.y,m1.z,m1.w,
                           m2.x,m2.y,m2.z,m2.w, m3.x,m3.y,m3.z,m3.w};
      const float2 v = ne[s];
      #pragma unroll
      for (int r = 0; r < 16; ++r) {
        acc[r][0] += m[r] * v.x;
        acc[r][1] += m[r] * v.y;
      }
    }
    #pragma unroll
    for (int r = 0; r < 16; ++r)                               // rel r: k in [128+128r, ...)
      *(unsigned int*)(arow + 256 + r * 256 + f0 * 2) = pk2_rne(acc[r][0], acc[r][1]);
  }
  barrier_full();                  // A_t ready; prestage + c0/c1 landed

  // ---------- Phase B: i=0,1 from LDS; i=2..16 reg-pipelined from L2 ----------
  f32x4 accA = {0.f,0.f,0.f,0.f}, accB = {0.f,0.f,0.f,0.f};
  {
    const char* ar = (const char*)A_t + ln * (LDA * 2) + lj * 16;
    const char* wl = smem + WLDS_OFF;
    #pragma unroll
    for (int i = 0; i < 2; ++i) {                              // LDS-served steps
      const short8 a  = *(const short8*)(ar + (ksq + i) * 64);
      const short8 b0v = *(const short8*)(wl + (((kq*2+i)*8 + ot0    ) * 1024) + l * 16);
      const short8 b1v = *(const short8*)(wl + (((kq*2+i)*8 + ot0 + 1) * 1024) + l * 16);
      accA = __builtin_amdgcn_mfma_f32_16x16x32_bf16(a, b0v, accA, 0, 0, 0);
      accB = __builtin_amdgcn_mfma_f32_16x16x32_bf16(a, b1v, accB, 0, 0, 0);
    }
    #pragma unroll
    for (int i = 2; i < 17; ++i) {                             // L2-served steps
      const short8 a = *(const short8*)(ar + (ksq + i) * 64);  // one read, two MFMAs
      const uint4 n0 = wq[0];                                  // prefetch i+1 (OOB-safe:
      const uint4 n1 = wq[64];                                 //  tail reads stay in d_ws)
      wq += 512;
      union { uint4 u; short8 s; } u0, u1;
      u0.u = c0; u1.u = c1;
      accA = __builtin_amdgcn_mfma_f32_16x16x32_bf16(a, u0.s, accA, 0, 0, 0);
      accB = __builtin_amdgcn_mfma_f32_16x16x32_bf16(a, u1.s, accB, 0, 0, 0);
      c0 = n0; c1 = n1;
    }
  }
  barrier_lgkm();                  // A_t dead; P0/P1 alias it

  // ---------- Phase C: kq even writes, kq odd accumulates ----------
  {
    float* Pg = P + (kq >> 1) * 2112;          // kq 0,1 -> P0 ; kq 2,3 -> P1
    if ((kq & 1) == 0) {
      #pragma unroll
      for (int j = 0; j < 4; ++j) {
        Pg[(lj*4+j)*132 + o0c] = accA[j];
        Pg[(lj*4+j)*132 + o1c] = accB[j];
      }
    }
    barrier_lgkm();
    if ((kq & 1) == 1) {
      #pragma unroll
      for (int j = 0; j < 4; ++j) {
        Pg[(lj*4+j)*132 + o0c] += accA[j];
        Pg[(lj*4+j)*132 + o1c] += accB[j];
      }
    }
    barrier_lgkm();
  }

  // ---------- Phase D: out = relu(P0 + P1) ----------
  {
    const int row = w;                         // t >> 6
    const int cc  = l * 2;
    const float2 pa = *(const float2*)(P + row * 132 + cc);
    const float2 pb = *(const float2*)(P + 2112 + row * 132 + cc);
    float2 o2;
    o2.x = fmaxf(pa.x + pb.x, 0.f);
    o2.y = fmaxf(pa.y + pb.y, 0.f);
    *(float2*)(out + (size_t)(b0 + row) * 128 + cc) = o2;
  }
}

extern "C" void kernel_launch(void* const* d_in, const int* in_sizes, int n_in,
                              void* d_out, int out_size, void* d_ws, size_t ws_size,
                              hipStream_t stream) {
  const float* emb       = (const float*)d_in[0];
  const float* w_self    = (const float*)d_in[1];
  const float* w_rel     = (const float*)d_in[2];
  const int*   nodes     = (const int*)d_in[3];
  const int*   neighbors = (const int*)d_in[4];
  const int*   rel_mask  = (const int*)d_in[5];
  float* out = (float*)d_out;
  (void)in_sizes; (void)n_in; (void)out_size; (void)ws_size;

  wprep<<<136, 256, 0, stream>>>(w_self, w_rel, (uint4*)d_ws);
  rgcn_fused<<<4096 / BT, NTHR, 0, stream>>>(
      emb, nodes, neighbors, rel_mask, (const uint4*)d_ws, out);
}

// Round 11
// 20.836 us; speedup vs baseline: 3.8111x; 1.0386x over previous
//
#include <hip/hip_runtime.h>
#include <hip/hip_bf16.h>

// RGCN fused: out = relu( [x | agg_r0..agg_r15] @ [w_self | w_rel]^T )
// B=4096, S=10, R=16, F=128, K_total=2176.
// v11 = v6 REVERT (best measured: 20.97 us). 256 blocks x 1024 thr (16
// waves = 4/SIMD). lgkm-only barriers keep W2/gather loads in flight across
// barriers. Phase B: wave = 2 o-tiles x 17 k-steps, 1-deep W2 reg pipeline
// from the wprep-packed bf16 fragment layout (coalescing-critical, R8).
// Ceiling accounting (R5/R9/R10): ~10us harness floor + ~3us wprep+gap +
// ~8us main (phase B at the 143MB/34.5TB/s L2 roofline).

#define BT   16
#define LDA  2184            // bf16 elems per A_t row (2176 + 8 pad)
#define NTHR 1024

typedef __attribute__((ext_vector_type(8))) short short8;  // 8 bf16
typedef __attribute__((ext_vector_type(4))) float f32x4;   // MFMA acc

__device__ __forceinline__ unsigned int pk2_rne(float lo, float hi) {
  unsigned int r;
  asm("v_cvt_pk_bf16_f32 %0, %1, %2" : "=v"(r) : "v"(lo), "v"(hi));
  return r;
}

// Workgroup barrier that drains LDS ops only — leaves global loads (W2
// prefetch, gathers) in flight across the barrier.
__device__ __forceinline__ void barrier_lgkm() {
  __builtin_amdgcn_sched_barrier(0);
  asm volatile("s_waitcnt lgkmcnt(0)" ::: "memory");
  __builtin_amdgcn_s_barrier();
  __builtin_amdgcn_sched_barrier(0);
}

// ---- prep: W (fp32) -> bf16 fragments, layout [ks][ot][lane], 16B/lane ----
__global__ __launch_bounds__(256)
void wprep(const float* __restrict__ w_self, const float* __restrict__ w_rel,
           uint4* __restrict__ w2)
{
  const int u  = blockIdx.x * 4 + (threadIdx.x >> 6);   // 0..543
  const int l  = threadIdx.x & 63;
  const int ln = l & 15, lj = l >> 4;
  const int ks = u >> 3, ot = u & 7;
  const int o  = ot * 16 + ln;
  const int k0 = ks * 32 + lj * 8;
  const float* src;
  if (k0 < 128) src = w_self + o * 128 + k0;
  else {
    const int r = (k0 - 128) >> 7, kc = (k0 - 128) & 127;
    src = w_rel + ((size_t)(r * 128 + o)) * 128 + kc;
  }
  const float4 a = *(const float4*)src;
  const float4 b = *(const float4*)(src + 4);
  uint4 v;
  v.x = pk2_rne(a.x, a.y); v.y = pk2_rne(a.z, a.w);
  v.z = pk2_rne(b.x, b.y); v.w = pk2_rne(b.z, b.w);
  w2[u * 64 + l] = v;
}

__global__ __launch_bounds__(NTHR)
void rgcn_fused(const float* __restrict__ emb,
                const int*   __restrict__ nodes,
                const int*   __restrict__ neighbors,
                const int*   __restrict__ rel_mask,
                const uint4* __restrict__ w2,
                float*       __restrict__ out)
{
  __shared__ alignas(16) char smem[80128];
  unsigned short* A_t = (unsigned short*)smem;                  // [16][2184] bf16
  float* P = (float*)smem;                                      // P0 [16][132]; P1 at +2112 words
  float (*mscale)[10][16] = (float (*)[10][16])(smem + 69888);  // [16][10][16]

  const int t  = threadIdx.x;
  const int l  = t & 63;
  const int w  = t >> 6;           // wave 0..15
  const int b0 = blockIdx.x * BT;

  // phase-B identity: wave = (o-group of 2 tiles) x (k-quarter of 17 ks)
  const int og  = w & 3,  kq = w >> 2;
  const int ot0 = og * 2;
  const int ksq = kq * 17;

  // ---------- index loads (first: gathers depend on them) ----------
  const int bi   = w;              // node slot 0..15 (one per wave)
  const int b    = b0 + bi;
  const int node = nodes[b];
  int nb[10];
  {
    const int2* np = (const int2*)(neighbors + (size_t)b * 10);  // 8B-aligned (40B stride)
    const int2 p0 = np[0], p1 = np[1], p2 = np[2], p3 = np[3], p4 = np[4];
    nb[0]=p0.x; nb[1]=p0.y; nb[2]=p1.x; nb[3]=p1.y; nb[4]=p2.x;
    nb[5]=p2.y; nb[6]=p3.x; nb[7]=p3.y; nb[8]=p4.x; nb[9]=p4.y;
  }

  // ---------- mask loads (waves 0-3 cover 16 nodes x 16 relations) ----------
  int mb[10];
  if (t < 256) {
    const int* mp = rel_mask + (size_t)(b0 + (t >> 4)) * 160 + (t & 15);
    #pragma unroll
    for (int s = 0; s < 10; ++s) mb[s] = mp[s * 16];
  }

  // ---------- W2 prefetch: this wave's first k-step (both o-tiles) ----------
  const uint4* wq = w2 + (size_t)((ksq * 8 + ot0) * 64) + l;
  uint4 c0 = wq[0];                // (ksq, ot0)
  uint4 c1 = wq[64];               // (ksq, ot0+1)
  wq += 512;                       // next k-step

  // ---------- gathers (issued early; consumed in phase A) ----------
  const int f0 = l * 2;            // 2 features per lane
  float2 ne[10];
  #pragma unroll
  for (int s = 0; s < 10; ++s)
    ne[s] = *(const float2*)(emb + (size_t)nb[s] * 128 + f0);
  const float2 x2 = *(const float2*)(emb + (size_t)node * 128 + f0);

  // ---------- mscale[b][s][r] = m/(count+eps) ----------
  if (t < 256) {
    int c = 0;
    #pragma unroll
    for (int s = 0; s < 10; ++s) c += mb[s];
    const float inv = 1.0f / ((float)c + 1e-10f);
    #pragma unroll
    for (int s = 0; s < 10; ++s) mscale[t >> 4][s][t & 15] = mb[s] ? inv : 0.0f;
  }
  barrier_lgkm();

  // ---------- Phase A: wave w builds A_t row w (self + 16 masked means) ----------
  {
    char* arow = (char*)A_t + bi * (LDA * 2);
    *(unsigned int*)(arow + f0 * 2) = pk2_rne(x2.x, x2.y);     // self, k in [0,128)
    float acc[16][2];
    #pragma unroll
    for (int r = 0; r < 16; ++r) { acc[r][0] = 0.f; acc[r][1] = 0.f; }
    #pragma unroll
    for (int s = 0; s < 10; ++s) {
      const float4 m0 = *(const float4*)(&mscale[bi][s][0]);   // uniform -> LDS broadcast
      const float4 m1 = *(const float4*)(&mscale[bi][s][4]);
      const float4 m2 = *(const float4*)(&mscale[bi][s][8]);
      const float4 m3 = *(const float4*)(&mscale[bi][s][12]);
      const float m[16] = {m0.x,m0.y,m0.z,m0.w, m1.x,m1.y,m1.z,m1.w,
                           m2.x,m2.y,m2.z,m2.w, m3.x,m3.y,m3.z,m3.w};
      const float2 v = ne[s];
      #pragma unroll
      for (int r = 0; r < 16; ++r) {
        acc[r][0] += m[r] * v.x;
        acc[r][1] += m[r] * v.y;
      }
    }
    #pragma unroll
    for (int r = 0; r < 16; ++r)                               // rel r: k in [128+128r, ...)
      *(unsigned int*)(arow + 256 + r * 256 + f0 * 2) = pk2_rne(acc[r][0], acc[r][1]);
  }
  barrier_lgkm();

  // ---------- Phase B: 17 k-steps x 2 o-tiles, 1-deep W2 reg pipeline ----------
  const int ln = l & 15, lj = l >> 4;
  f32x4 accA = {0.f,0.f,0.f,0.f}, accB = {0.f,0.f,0.f,0.f};
  {
    const char* ar = (const char*)A_t + ln * (LDA * 2) + lj * 16;
    #pragma unroll
    for (int i = 0; i < 17; ++i) {
      const short8 a = *(const short8*)(ar + (ksq + i) * 64);  // one read, two MFMAs
      const uint4 n0 = wq[0];                                  // prefetch ks+1 (OOB-safe
      const uint4 n1 = wq[64];                                 //  tail reads land in d_ws)
      wq += 512;
      union { uint4 u; short8 s; } u0, u1;
      u0.u = c0; u1.u = c1;
      accA = __builtin_amdgcn_mfma_f32_16x16x32_bf16(a, u0.s, accA, 0, 0, 0);
      accB = __builtin_amdgcn_mfma_f32_16x16x32_bf16(a, u1.s, accB, 0, 0, 0);
      c0 = n0; c1 = n1;
    }
  }
  barrier_lgkm();                  // A_t dead; P0/P1 alias it

  // ---------- Phase C: kq even writes, kq odd accumulates ----------
  {
    const int o0c = ot0 * 16 + ln;
    const int o1c = o0c + 16;
    float* Pg = P + (kq >> 1) * 2112;          // kq 0,1 -> P0 ; kq 2,3 -> P1
    if ((kq & 1) == 0) {
      #pragma unroll
      for (int j = 0; j < 4; ++j) {
        Pg[(lj*4+j)*132 + o0c] = accA[j];
        Pg[(lj*4+j)*132 + o1c] = accB[j];
      }
    }
    barrier_lgkm();
    if ((kq & 1) == 1) {
      #pragma unroll
      for (int j = 0; j < 4; ++j) {
        Pg[(lj*4+j)*132 + o0c] += accA[j];
        Pg[(lj*4+j)*132 + o1c] += accB[j];
      }
    }
    barrier_lgkm();
  }

  // ---------- Phase D: out = relu(P0 + P1) ----------
  {
    const int row = w;                         // t >> 6
    const int cc  = (t & 63) * 2;
    const float2 pa = *(const float2*)(P + row * 132 + cc);
    const float2 pb = *(const float2*)(P + 2112 + row * 132 + cc);
    float2 o2;
    o2.x = fmaxf(pa.x + pb.x, 0.f);
    o2.y = fmaxf(pa.y + pb.y, 0.f);
    *(float2*)(out + (size_t)(b0 + row) * 128 + cc) = o2;
  }
}

extern "C" void kernel_launch(void* const* d_in, const int* in_sizes, int n_in,
                              void* d_out, int out_size, void* d_ws, size_t ws_size,
                              hipStream_t stream) {
  const float* emb       = (const float*)d_in[0];
  const float* w_self    = (const float*)d_in[1];
  const float* w_rel     = (const float*)d_in[2];
  const int*   nodes     = (const int*)d_in[3];
  const int*   neighbors = (const int*)d_in[4];
  const int*   rel_mask  = (const int*)d_in[5];
  float* out = (float*)d_out;
  (void)in_sizes; (void)n_in; (void)out_size; (void)ws_size;

  wprep<<<136, 256, 0, stream>>>(w_self, w_rel, (uint4*)d_ws);
  rgcn_fused<<<4096 / BT, NTHR, 0, stream>>>(
      emb, nodes, neighbors, rel_mask, (const uint4*)d_ws, out);
}